// Round 11
// baseline (1398.796 us; speedup 1.0000x reference)
//
#include <hip/hip_runtime.h>

// Sinkhorn entropic OT, B=16, N=2048, d=3, EPS=0.02, 20 iterations.
// out = (10/16) * sum_b sum_ij P_ij C_ij
//
// R11 (from R10's A/B: harness stable, R5 structure = bit-exact; profile says
// LDS-ISSUE-bound: 512 wave-uniform ds_read_b128/wave/phase, 8 waves/CU
// ~20.4us/phase vs VALU ~13us): each ds_read now feeds TWO rows per lane
// (rows l and l+64), 128 rows/block, 256 blocks (1/CU, 4 waves) -> LDS issue
// halves. ALL per-row FP chains are bit-identical to R5 (same 4x512 slice
// partition, same chunk-16 tree/rescale/sum, same cross-slice combine order);
// final pass = two sequential R5-exact sub-passes so the 512 atomicAdd
// partials are the exact R5 multiset (atomic-order robustness replay-proven).
// Data path stays LDS-staged (global-direct reads failed R7/R8 by 1 ulp);
// arrive_and_wait is R5-verbatim.

namespace {
constexpr int BATCH = 16;
constexpr int NPT   = 2048;
constexpr int BLOCKS_PER_BATCH = 16;        // 128 rows per block
constexpr int ROWS_PER_BLOCK   = 128;       // 2 rows per lane
constexpr int NSLICE = 4;                   // j-slices per block (one per wave)
constexpr int JSLICE = NPT / NSLICE;        // 512 j's per lane-task per phase
constexpr int NBLOCKS  = BATCH * BLOCKS_PER_BATCH;   // 256 (= 1 block/CU)
constexpr int NTHREADS = 256;
constexpr int ITERS = 20;
constexpr int CHUNK = 16;

constexpr int BAR_STRIDE = 32;              // uints between counters (128B pad)
constexpr int BAR_BYTES  = 4096;            // zeroed via hipMemsetAsync pre-launch

constexpr float SCL     = 72.13475204444817f;     // log2(e)/eps
constexpr float TWOS    = 144.26950408889634f;    // 2*SCL
constexpr float UCONST  = -11.0f;                 // logmu*log2e = -log2(2048)
constexpr float Q_CONST = -22.0f;                 // (logmu+lognu)*log2e

__device__ inline float fexp2(float x) { return __builtin_amdgcn_exp2f(x); }

struct Smem {
  float4 tab[NPT];                       // 32 KB staged table (4 slices)
  float  redM[NSLICE * ROWS_PER_BLOCK];  // 2 KB
  float  redS[NSLICE * ROWS_PER_BLOCK];  // 2 KB
  float  wsum[4];
};

// R5-verbatim inter-block arrive-and-wait (acquire IS the spin condition).
__device__ inline void arrive_and_wait(unsigned* bar, unsigned target, int tid) {
  __syncthreads();                        // block done with previous phase
  if (tid == 0) {
    __hip_atomic_fetch_add(bar, 1u, __ATOMIC_RELEASE, __HIP_MEMORY_SCOPE_AGENT);
    while (__hip_atomic_load(bar, __ATOMIC_ACQUIRE, __HIP_MEMORY_SCOPE_AGENT) < target) {}
  }
  __syncthreads();                        // all threads see the acquire
}

// R5-exact per-chunk LSE update: max tree pairing, rescale, even/odd sums.
__device__ inline void lse_chunk(const float (&z)[CHUNK], float& m, float& s0, float& s1) {
  float m0 = fmaxf(fmaxf(z[0],  z[1]),  z[2]);
  float m1 = fmaxf(fmaxf(z[3],  z[4]),  z[5]);
  float m2 = fmaxf(fmaxf(z[6],  z[7]),  z[8]);
  float m3 = fmaxf(fmaxf(z[9],  z[10]), z[11]);
  float m4 = fmaxf(fmaxf(z[12], z[13]), z[14]);
  float mn = fmaxf(fmaxf(fmaxf(m0, m1), m2), fmaxf(fmaxf(m3, m4), z[15]));
  float mN = fmaxf(m, mn);
  float r = fexp2(m - mN);   // 0 on first chunk (m=-3e38), 1 when no new max
  s0 *= r; s1 *= r;
  m = mN;
#pragma unroll
  for (int k = 0; k < CHUNK; k += 2) {
    s0 += fexp2(z[k] - m);
    s1 += fexp2(z[k + 1] - m);
  }
}

// Stage wave's slice into LDS (R5 pattern), then streaming LSE for TWO rows
// per lane off each ds_read. Per-row FP chains identical to R5.
__device__ inline void half_phase(float pA0, float pA1, float pA2,
                                  float pB0, float pB1, float pB2,
                                  const float4* __restrict__ T,
                                  float4* __restrict__ outT,
                                  Smem& sm,
                                  int batch, int rowBase, int slice, int lane, int tid) {
  // ---- stage: 8 coalesced float4 loads per lane (R5-identical pattern)
  {
    const float4* __restrict__ gsrc = T + (size_t)batch * NPT + slice * JSLICE;
    float4* __restrict__ ldst = sm.tab + slice * JSLICE;
#pragma unroll
    for (int k = 0; k < JSLICE / 64; ++k)
      ldst[k * 64 + lane] = gsrc[k * 64 + lane];
  }
  __syncthreads();   // orders ds_write -> ds_read

  const float aA0 = pA0 * TWOS, aA1 = pA1 * TWOS, aA2 = pA2 * TWOS;
  const float aB0 = pB0 * TWOS, aB1 = pB1 * TWOS, aB2 = pB2 * TWOS;
  const float4* __restrict__ tb = sm.tab + slice * JSLICE;

  float mA = -3.0e38f, sA0 = 0.f, sA1 = 0.f;
  float mB = -3.0e38f, sB0 = 0.f, sB1 = 0.f;
  for (int c = 0; c < JSLICE; c += CHUNK) {
    float zA[CHUNK], zB[CHUNK];
#pragma unroll
    for (int k = 0; k < CHUNK; ++k) {
      float4 t = tb[c + k];               // ONE wave-uniform ds_read_b128, 2 rows
      zA[k] = fmaf(aA0, t.x, fmaf(aA1, t.y, fmaf(aA2, t.z, t.w)));
      zB[k] = fmaf(aB0, t.x, fmaf(aB1, t.y, fmaf(aB2, t.z, t.w)));
    }
    lse_chunk(zA, mA, sA0, sA1);
    lse_chunk(zB, mB, sB0, sB1);
  }

  sm.redM[slice * ROWS_PER_BLOCK + lane] = mA;
  sm.redS[slice * ROWS_PER_BLOCK + lane] = sA0 + sA1;
  sm.redM[slice * ROWS_PER_BLOCK + 64 + lane] = mB;
  sm.redS[slice * ROWS_PER_BLOCK + 64 + lane] = sB0 + sB1;
  __syncthreads();
  if (tid < ROWS_PER_BLOCK) {
    float M = sm.redM[tid], S = sm.redS[tid];
#pragma unroll
    for (int q = 1; q < NSLICE; ++q) {
      float m2q = sm.redM[q * ROWS_PER_BLOCK + tid];
      float s2q = sm.redS[q * ROWS_PER_BLOCK + tid];
      float Mn = fmaxf(M, m2q);
      S = fmaf(S, fexp2(M - Mn), s2q * fexp2(m2q - Mn));
      M = Mn;
    }
    float u = UCONST - (M + __log2f(S));      // == (pot - |p|^2) * SCL
    // thread tid<64 (wave 0) holds pA of row rowBase+tid;
    // thread tid in [64,128) (wave 1) holds pB of row rowBase+tid.
    float w0 = (tid < 64) ? pA0 : pB0;
    float w1 = (tid < 64) ? pA1 : pB1;
    float w2 = (tid < 64) ? pA2 : pB2;
    outT[batch * NPT + rowBase + tid] = make_float4(w0, w1, w2, u);
  }
  // no trailing barrier: an arrive_and_wait follows every phase
}

__global__ __launch_bounds__(NTHREADS, 1)
void sinkhorn_emd_kernel(const float* __restrict__ X, const float* __restrict__ Y,
                         float* __restrict__ ws, float* __restrict__ out) {
  unsigned* __restrict__ bars = (unsigned*)ws;            // [1024] zeroed pre-launch
  float4* tF = (float4*)((char*)ws + BAR_BYTES);          // [B*N]: (y, u_j)
  float4* tG = tF + BATCH * NPT;                          // [B*N]: (x, u_i)

  const int tid  = threadIdx.x;
  const int bid  = blockIdx.x;
  const int gtid = bid * NTHREADS + tid;

  __shared__ Smem sm;

  // ---- init: tableF from y with g=0 (same values as R5); zero out ----
  if (gtid < BATCH * NPT) {
    const float* yp = Y + (size_t)gtid * 3;
    float y0 = yp[0], y1 = yp[1], y2 = yp[2];
    float yy = fmaf(y0, y0, fmaf(y1, y1, y2 * y2));
    tF[gtid] = make_float4(y0, y1, y2, -yy * SCL);   // u_j = (0 - yy)*S
  }
  if (gtid == 0) out[0] = 0.f;

  // XCD-batch affinity: bid&7 == XCD; 2 batches per XCD, 16 blocks per batch.
  const int xcd   = bid & 7;
  const int slot  = bid >> 3;                       // 0..31
  const int batch = xcd * 2 + (slot >> 4);          // 2 batches per XCD
  const int rb    = slot & (BLOCKS_PER_BATCH - 1);  // 0..15
  const int lane  = tid & 63;
  const int slice = tid >> 6;
  const int rowBase = rb * ROWS_PER_BLOCK;
  const int rowA  = rowBase + lane;
  const int rowB  = rowA + 64;

  // hoist this lane's two x-rows and two y-rows
  const float* xa = X + (size_t)(batch * NPT + rowA) * 3;
  const float pxA0 = xa[0], pxA1 = xa[1], pxA2 = xa[2];
  const float* xb = X + (size_t)(batch * NPT + rowB) * 3;
  const float pxB0 = xb[0], pxB1 = xb[1], pxB2 = xb[2];
  const float* ya = Y + (size_t)(batch * NPT + rowA) * 3;
  const float pyA0 = ya[0], pyA1 = ya[1], pyA2 = ya[2];
  const float* yb = Y + (size_t)(batch * NPT + rowB) * 3;
  const float pyB0 = yb[0], pyB1 = yb[1], pyB2 = yb[2];

  // one global barrier: orders init (tables + out[0]) before everything
  arrive_and_wait(bars + 512, NBLOCKS, tid);

  unsigned* __restrict__ bar = bars + batch * BAR_STRIDE;
  unsigned targ = BLOCKS_PER_BATCH;

  for (int it = 0; it < ITERS; ++it) {
    // F: f_i from stream over (y, g)  -> writes tG
    half_phase(pxA0, pxA1, pxA2, pxB0, pxB1, pxB2, tF, tG, sm,
               batch, rowBase, slice, lane, tid);
    arrive_and_wait(bar, targ, tid); targ += BLOCKS_PER_BATCH;
    // G: g_j from stream over (x, f)  -> writes tF
    half_phase(pyA0, pyA1, pyA2, pyB0, pyB1, pyB2, tG, tF, sm,
               batch, rowBase, slice, lane, tid);
    arrive_and_wait(bar, targ, tid); targ += BLOCKS_PER_BATCH;
  }

  // ---- final: two sequential R5-exact sub-passes (rows +0..64, +64..128) ----
  {
    {
      const float4* __restrict__ gsrc = tF + (size_t)batch * NPT + slice * JSLICE;
      float4* __restrict__ ldst = sm.tab + slice * JSLICE;
#pragma unroll
      for (int k = 0; k < JSLICE / 64; ++k)
        ldst[k * 64 + lane] = gsrc[k * 64 + lane];
    }
    __syncthreads();

    const float4* __restrict__ tb = sm.tab + slice * JSLICE;

    auto final_sub = [&](float p0, float p1, float p2, int rowH) {
      const float nrm = fmaf(p0, p0, fmaf(p1, p1, p2 * p2));
      const float q = tG[batch * NPT + rowH].w + Q_CONST;    // per-lane load
      float acc = 0.f;
      for (int c = 0; c < JSLICE; c += 4) {
#pragma unroll
        for (int k = 0; k < 4; ++k) {
          float4 t = tb[c + k];
          float dot = fmaf(p2, t.z, fmaf(p1, t.y, p0 * t.x));
          float yy  = fmaf(t.z, t.z, fmaf(t.y, t.y, t.x * t.x));
          float Cij = fmaf(-2.f, dot, nrm + yy);
          float lp  = fmaf(TWOS, dot, q + t.w);        // logP * log2e
          acc = fmaf(fexp2(lp), Cij, acc);
        }
      }
      for (int off = 32; off; off >>= 1) acc += __shfl_down(acc, off, 64);
      if ((tid & 63) == 0) sm.wsum[tid >> 6] = acc;
      __syncthreads();
      if (tid == 0) {
        float tot = 0.f;
#pragma unroll
        for (int k = 0; k < 4; ++k) tot += sm.wsum[k];
        atomicAdd(out, 0.625f * tot);   // 10/16 — same multiset as R5's blocks
      }
      __syncthreads();   // protect wsum before next sub-pass overwrites
    };

    final_sub(pxA0, pxA1, pxA2, rowBase + lane);        // == R5 block 2rb
    final_sub(pxB0, pxB1, pxB2, rowBase + 64 + lane);   // == R5 block 2rb+1
  }
}
} // namespace

extern "C" void kernel_launch(void* const* d_in, const int* in_sizes, int n_in,
                              void* d_out, int out_size, void* d_ws, size_t ws_size,
                              hipStream_t stream) {
  const float* X = (const float*)d_in[0];
  const float* Y = (const float*)d_in[1];
  float* out = (float*)d_out;
  float* ws  = (float*)d_ws;

  // zero the barrier counters (ws is poisoned 0xAA before every launch)
  hipMemsetAsync(ws, 0, BAR_BYTES, stream);

  void* args[] = {(void*)&X, (void*)&Y, (void*)&ws, (void*)&out};
  hipLaunchCooperativeKernel((const void*)sinkhorn_emd_kernel,
                             dim3(NBLOCKS), dim3(NTHREADS),
                             args, 0, stream);
}